// Round 6
// baseline (153.145 us; speedup 1.0000x reference)
//
#include <hip/hip_runtime.h>
#include <math.h>

// ===================== windowed x-sorted path =====================
#define NBIN   512
#define BEXT   64.0f          // bins cover [-64,64], width 0.25 (all exact in f32)
#define WQPB   64             // queries per search block
#define WTH    256            // 4 waves
#define WWAVES 4
#define WCHUNK 1024           // staged points per LDS pass
#define WSLACK 0.02f          // covers d2 cancellation error (<=~3e-3) + bin-edge fp slop
#define BTH1   1024           // build threads

__device__ __forceinline__ int bin1(float x) {
    int c = (int)floorf((x + BEXT) * 4.0f);
    return min(NBIN - 1, max(0, c));
}
// monotone float->uint fold (handles tiny negative d2 from rounding correctly)
__device__ __forceinline__ unsigned f2sort(float f) {
    int b = __float_as_int(f);
    return (unsigned)b ^ (0x80000000u | (unsigned)(b >> 31));
}
__device__ __forceinline__ float sort2f(unsigned u) {
    unsigned b = (u & 0x80000000u) ? (u ^ 0x80000000u) : ~u;
    return __uint_as_float(b);
}
__device__ __forceinline__ void ins3k(unsigned long long k,
                                      unsigned long long& k0,
                                      unsigned long long& k1,
                                      unsigned long long& k2) {
    const bool c0 = k < k0, c1 = k < k1, c2 = k < k2;
    k2 = c1 ? k1 : (c2 ? k : k2);
    k1 = c0 ? k0 : (c1 ? k : k1);
    k0 = c0 ? k  : k0;
}

// ---- 1-D counting sort: blocks [0,B) bin points, [B,2B) bin queries ----
extern "C" __global__ void __launch_bounds__(BTH1)
build1d(const float* __restrict__ xyz, const float* __restrict__ nxyz,
        int mb, int nb,
        float4* __restrict__ ps, int* __restrict__ pidx,
        int* __restrict__ qord, int* __restrict__ boff)
{
    __shared__ int hist[NBIN];
    __shared__ int scanb[NBIN];
    const int B    = (int)gridDim.x / 2;
    const bool isQ = (int)blockIdx.x >= B;
    const int b    = isQ ? (int)blockIdx.x - B : (int)blockIdx.x;
    const int tid  = threadIdx.x;
    const int n    = isQ ? nb : mb;
    const float* P = (isQ ? nxyz : xyz) + (size_t)b * n * 3;

    if (tid < NBIN) hist[tid] = 0;
    __syncthreads();
    for (int i = tid; i < n; i += BTH1) atomicAdd(&hist[bin1(P[i * 3])], 1);
    __syncthreads();
    int h = 0;
    if (tid < NBIN) { h = hist[tid]; scanb[tid] = h; }
    __syncthreads();
    for (int off = 1; off < NBIN; off <<= 1) {
        int t = 0;
        if (tid < NBIN && tid >= off) t = scanb[tid - off];
        __syncthreads();
        if (tid < NBIN) scanb[tid] += t;
        __syncthreads();
    }
    if (tid < NBIN) {
        const int excl = scanb[tid] - h;      // exclusive
        if (!isQ) {
            boff[(size_t)b * (NBIN + 1) + tid] = excl;
            if (tid == NBIN - 1) boff[(size_t)b * (NBIN + 1) + NBIN] = n;
        }
        hist[tid] = excl;                     // reuse as scatter cursor
    }
    __syncthreads();
    for (int i = tid; i < n; i += BTH1) {
        const float x = P[i * 3], y = P[i * 3 + 1], z = P[i * 3 + 2];
        const int c = bin1(x);
        const int pos = atomicAdd(&hist[c], 1);
        if (isQ) {
            qord[(size_t)b * nb + pos] = i;
        } else {
            float pn;
            {
#pragma clang fp contract(off)
                pn = (x * x + y * y) + z * z;  // matches np.sum(known*known,-1)
            }
            ps[(size_t)b * mb + pos]   = make_float4(x, y, z, pn);
            pidx[(size_t)b * mb + pos] = i;    // original (tie-break) index
        }
    }
}

// ---- windowed search + interpolate: block = 64 x-sorted queries ----
extern "C" __global__ void __launch_bounds__(WTH)
knn_win(const float* __restrict__ nxyz, const float* __restrict__ feats,
        const int* __restrict__ qord, const int* __restrict__ boff,
        const float4* __restrict__ ps, const int* __restrict__ pidx,
        float* __restrict__ out, int mb, int nb, int C)
{
    __shared__ float4 s_pts[WCHUNK];
    __shared__ int    s_idx[WCHUNK];
    __shared__ float  sPB[WWAVES][WQPB];
    __shared__ unsigned long long sMK[WWAVES][3][WQPB];
    __shared__ float sW[3][WQPB];
    __shared__ int   sF[3][WQPB];
    __shared__ int   sRow[WQPB];
    __shared__ int   sNeed[2];

    const int tid = threadIdx.x;
    const int w   = tid >> 6;
    const int l   = tid & 63;
    const int s0  = blockIdx.x * WQPB;         // global q_order position
    const int b   = s0 / nb;

    const int qloc = qord[s0 + l];             // every wave holds all 64 queries
    const int row  = b * nb + qloc;
    const float qx = nxyz[(size_t)row * 3 + 0];
    const float qy = nxyz[(size_t)row * 3 + 1];
    const float qz = nxyz[(size_t)row * 3 + 2];
    float qq;
    {
#pragma clang fp contract(off)
        qq = (qx * qx + qy * qy) + qz * qz;    // matches np.sum(query*query,-1)
    }

    // block x-range (identical per wave via full-wave butterfly)
    float mn = qx, mx = qx;
#pragma unroll
    for (int m = 1; m < 64; m <<= 1) {
        mn = fminf(mn, __shfl_xor(mn, m, 64));
        mx = fmaxf(mx, __shfl_xor(mx, m, 64));
    }

    const int*    boffb = boff + (size_t)b * (NBIN + 1);
    const float4* psb   = ps   + (size_t)b * mb;
    const int*    pib   = pidx + (size_t)b * mb;

    unsigned long long k0 = ~0ull, k1 = ~0ull, k2 = ~0ull;

    // scan a contiguous range of the x-sorted array (v5 structure: LDS chunks,
    // wave-sliced, wave-uniform broadcast reads, u64 lex keys -> order-invariant)
    auto scan = [&](int lo, int hi) {
        for (int base = lo; base < hi; base += WCHUNK) {
            const int cnt = min(WCHUNK, hi - base);
            __syncthreads();                       // prior readers done
            for (int i = tid; i < cnt; i += WTH) {
                s_pts[i] = psb[base + i];
                s_idx[i] = pib[base + i];
            }
            __syncthreads();
            const int a = (w * cnt) / WWAVES;
            const int e = ((w + 1) * cnt) / WWAVES;
#pragma unroll 4
            for (int p = a; p < e; ++p) {
                const float4 Pt = s_pts[p];        // broadcast
                const int    pi = s_idx[p];        // broadcast
                const float dot = fmaf(qz, Pt.z, fmaf(qy, Pt.y, qx * Pt.x));
                const float d2  = fmaf(-2.0f, dot, qq) + Pt.w;  // EXACT ref rounding
                const unsigned long long key =
                    ((unsigned long long)f2sort(d2) << 32) | (unsigned)pi;
                ins3k(key, k0, k1, k2);
            }
        }
    };

    float W = 2.0f;
    int blo = bin1(mn - W), bhi = bin1(mx + W);
    scan(boffb[blo], boffb[bhi + 1]);

    for (int iter = 0; iter < 12; ++iter) {
        // conservative stop bound: ub = min over waves of partial 3rd-best
        const unsigned hi2 = (unsigned)(k2 >> 32);
        sPB[w][l] = (hi2 == 0xFFFFFFFFu) ? INFINITY : sort2f(hi2);
        if (tid == 0) { sNeed[0] = 0; sNeed[1] = 0; }
        __syncthreads();
        if (tid < WQPB) {
            const float ub = fminf(fminf(sPB[0][tid], sPB[1][tid]),
                                   fminf(sPB[2][tid], sPB[3][tid]));
            const float eL = fmaf(0.25f, (float)blo, -BEXT);       // exact bin edges
            const float eR = fmaf(0.25f, (float)(bhi + 1), -BEXT);
            const float gL = qx - eL;                               // thread tid == query tid
            const float gR = eR - qx;
            if (blo > 0        && !(gL * gL > ub + WSLACK)) sNeed[0] = 1;
            if (bhi < NBIN - 1 && !(gR * gR > ub + WSLACK)) sNeed[1] = 1;
        }
        __syncthreads();
        const bool anyL = sNeed[0] != 0, anyR = sNeed[1] != 0;
        __syncthreads();                          // all read flags before next writes
        if (!anyL && !anyR) break;
        W *= 2.0f;
        const int tblo = anyL ? bin1(mn - W) : blo;
        const int tbhi = anyR ? bin1(mx + W) : bhi;
        if (tblo < blo) scan(boffb[tblo], boffb[blo]);          // disjoint deltas:
        if (tbhi > bhi) scan(boffb[bhi + 1], boffb[tbhi + 1]);  // no double-count
        blo = tblo; bhi = tbhi;
    }

    // merge 4 per-wave triples (keys are globally unique -> exact lex top-3)
    sMK[w][0][l] = k0; sMK[w][1][l] = k1; sMK[w][2][l] = k2;
    __syncthreads();
    if (tid < WQPB) {
        unsigned long long m0 = sMK[0][0][tid], m1 = sMK[0][1][tid], m2 = sMK[0][2][tid];
        for (int w2 = 1; w2 < WWAVES; ++w2) {
            ins3k(sMK[w2][0][tid], m0, m1, m2);
            ins3k(sMK[w2][1][tid], m0, m1, m2);
            ins3k(sMK[w2][2][tid], m0, m1, m2);
        }
        const float d0 = sort2f((unsigned)(m0 >> 32));
        const float d1 = sort2f((unsigned)(m1 >> 32));
        const float d2v = sort2f((unsigned)(m2 >> 32));
        // weights (reference: sqrt(max(d2,0)), recip(+1e-8), normalize)
        const float da = sqrtf(fmaxf(d0, 0.0f));
        const float db = sqrtf(fmaxf(d1, 0.0f));
        const float dc = sqrtf(fmaxf(d2v, 0.0f));
        const float ra = 1.0f / (da + 1e-8f);
        const float rb = 1.0f / (db + 1e-8f);
        const float rc = 1.0f / (dc + 1e-8f);
        float rs;
        {
#pragma clang fp contract(off)
            rs = (ra + rb) + rc;
        }
        sW[0][tid] = ra / rs;  sW[1][tid] = rb / rs;  sW[2][tid] = rc / rs;
        sF[0][tid] = b * mb + (int)(unsigned)(m0 & 0xFFFFFFFFu);
        sF[1][tid] = b * mb + (int)(unsigned)(m1 & 0xFFFFFFFFu);
        sF[2][tid] = b * mb + (int)(unsigned)(m2 & 0xFFFFFFFFu);
        sRow[tid]  = row;
    }
    __syncthreads();

    // fused interpolation: wave per 16 queries, lanes = channels (coalesced)
    const int qpw = WQPB / WWAVES;                 // 16
    for (int j = 0; j < qpw; ++j) {
        const int q = w * qpw + j;
        const float wa = sW[0][q], wb = sW[1][q], wc = sW[2][q];
        const size_t ga = (size_t)sF[0][q] * C;
        const size_t gb = (size_t)sF[1][q] * C;
        const size_t gc = (size_t)sF[2][q] * C;
        const size_t go = (size_t)sRow[q] * C;
        for (int ch = l; ch < C; ch += 64) {
            out[go + ch] = wa * feats[ga + ch] + wb * feats[gb + ch] + wc * feats[gc + ch];
        }
    }
}

// ===================== round-5 brute path (kept as fallback) =====================
#define THREADS 512
#define WAVES   8
#define RQ      2
#define QPB     128
#define CHUNK   2048

extern "C" __global__ void __launch_bounds__(THREADS)
knn3_v5(const float* __restrict__ xyz,
        const float* __restrict__ new_xyz,
        const float* __restrict__ feats,
        float* __restrict__ out,
        int mb, int nb, int C)
{
    extern __shared__ float smem[];
    float4* s_pts = (float4*)smem;

    const int tid = threadIdx.x;
    const int w   = tid >> 6;
    const int l   = tid & 63;
    const int block_q0 = blockIdx.x * QPB;
    const int batch    = block_q0 / nb;
    const int known0   = batch * mb;

    float qx[RQ], qy[RQ], qz[RQ], qq[RQ];
#pragma unroll
    for (int r = 0; r < RQ; ++r) {
        const int gq = block_q0 + r * 64 + l;
        qx[r] = new_xyz[(size_t)gq * 3 + 0];
        qy[r] = new_xyz[(size_t)gq * 3 + 1];
        qz[r] = new_xyz[(size_t)gq * 3 + 2];
        {
#pragma clang fp contract(off)
            qq[r] = (qx[r] * qx[r] + qy[r] * qy[r]) + qz[r] * qz[r];
        }
    }
    float b0[RQ], b1[RQ], b2[RQ];
    int   i0[RQ], i1[RQ], i2[RQ];
#pragma unroll
    for (int r = 0; r < RQ; ++r) {
        b0[r] = INFINITY; b1[r] = INFINITY; b2[r] = INFINITY;
        i0[r] = 0; i1[r] = 0; i2[r] = 0;
    }
    const int nch = (mb + CHUNK - 1) / CHUNK;
    for (int c = 0; c < nch; ++c) {
        const int base = c * CHUNK;
        const int cnt  = min(CHUNK, mb - base);
        if (c > 0) __syncthreads();
        const float* src = xyz + (size_t)(known0 + base) * 3;
        for (int p = tid; p < cnt; p += THREADS) {
            const float px = src[p * 3 + 0];
            const float py = src[p * 3 + 1];
            const float pz = src[p * 3 + 2];
            float pn;
            {
#pragma clang fp contract(off)
                pn = (px * px + py * py) + pz * pz;
            }
            s_pts[p] = make_float4(px, py, pz, pn);
        }
        __syncthreads();
        const int lo = (w * cnt) / WAVES;
        const int hi = ((w + 1) * cnt) / WAVES;
#pragma unroll 4
        for (int p = lo; p < hi; ++p) {
            const float4 P = s_pts[p];
            const int gp = base + p;
#pragma unroll
            for (int r = 0; r < RQ; ++r) {
                const float dot = fmaf(qz[r], P.z, fmaf(qy[r], P.y, qx[r] * P.x));
                const float d2  = fmaf(-2.0f, dot, qq[r]) + P.w;
                const bool c0 = d2 < b0[r];
                const bool c1 = d2 < b1[r];
                const bool c2 = d2 < b2[r];
                const float n0 = fminf(d2, b0[r]);
                const float n1 = __builtin_amdgcn_fmed3f(d2, b0[r], b1[r]);
                const float n2 = __builtin_amdgcn_fmed3f(d2, b1[r], b2[r]);
                const int  j0 = c0 ? gp : i0[r];
                const int  j1 = c0 ? i0[r] : (c1 ? gp : i1[r]);
                const int  j2 = c1 ? i1[r] : (c2 ? gp : i2[r]);
                b0[r] = n0; b1[r] = n1; b2[r] = n2;
                i0[r] = j0; i1[r] = j1; i2[r] = j2;
            }
        }
    }
    __syncthreads();
    float* sB  = smem;
    int*   sI  = (int*)smem + 3 * WAVES * QPB;
    float* sFW = smem + 6 * WAVES * QPB;
    int*   sFI = (int*)sFW + 3 * QPB;
#pragma unroll
    for (int r = 0; r < RQ; ++r) {
        const int qb = r * 64 + l;
        sB[(0 * WAVES + w) * QPB + qb] = b0[r];
        sB[(1 * WAVES + w) * QPB + qb] = b1[r];
        sB[(2 * WAVES + w) * QPB + qb] = b2[r];
        sI[(0 * WAVES + w) * QPB + qb] = i0[r];
        sI[(1 * WAVES + w) * QPB + qb] = i1[r];
        sI[(2 * WAVES + w) * QPB + qb] = i2[r];
    }
    __syncthreads();
    if (tid < QPB) {
        float mv0 = sB[(0 * WAVES) * QPB + tid];
        float mv1 = sB[(1 * WAVES) * QPB + tid];
        float mv2 = sB[(2 * WAVES) * QPB + tid];
        int   mi0 = sI[(0 * WAVES) * QPB + tid];
        int   mi1 = sI[(1 * WAVES) * QPB + tid];
        int   mi2 = sI[(2 * WAVES) * QPB + tid];
        for (int c = 1; c < WAVES; ++c) {
#pragma unroll
            for (int k = 0; k < 3; ++k) {
                const float x  = sB[(k * WAVES + c) * QPB + tid];
                const int   xi = sI[(k * WAVES + c) * QPB + tid];
                const bool c0 = (x < mv0) || (x == mv0 && xi < mi0);
                const bool c1 = (x < mv1) || (x == mv1 && xi < mi1);
                const bool c2 = (x < mv2) || (x == mv2 && xi < mi2);
                const float n2 = c1 ? mv1 : (c2 ? x : mv2);
                const int   j2 = c1 ? mi1 : (c2 ? xi : mi2);
                const float n1 = c0 ? mv0 : (c1 ? x : mv1);
                const int   j1 = c0 ? mi0 : (c1 ? xi : mi1);
                const float n0 = c0 ? x : mv0;
                const int   j0 = c0 ? xi : mi0;
                mv0 = n0; mv1 = n1; mv2 = n2;
                mi0 = j0; mi1 = j1; mi2 = j2;
            }
        }
        const float da = sqrtf(fmaxf(mv0, 0.0f));
        const float db = sqrtf(fmaxf(mv1, 0.0f));
        const float dc = sqrtf(fmaxf(mv2, 0.0f));
        const float ra = 1.0f / (da + 1e-8f);
        const float rb = 1.0f / (db + 1e-8f);
        const float rc = 1.0f / (dc + 1e-8f);
        float rs;
        {
#pragma clang fp contract(off)
            rs = (ra + rb) + rc;
        }
        sFW[0 * QPB + tid] = ra / rs;
        sFW[1 * QPB + tid] = rb / rs;
        sFW[2 * QPB + tid] = rc / rs;
        sFI[0 * QPB + tid] = known0 + mi0;
        sFI[1 * QPB + tid] = known0 + mi1;
        sFI[2 * QPB + tid] = known0 + mi2;
    }
    __syncthreads();
    const int qpw = QPB / WAVES;
    for (int j = 0; j < qpw; ++j) {
        const int qi = w * qpw + j;
        const float wa = sFW[0 * QPB + qi];
        const float wb = sFW[1 * QPB + qi];
        const float wc = sFW[2 * QPB + qi];
        const size_t ga = (size_t)sFI[0 * QPB + qi] * C;
        const size_t gb = (size_t)sFI[1 * QPB + qi] * C;
        const size_t gc = (size_t)sFI[2 * QPB + qi] * C;
        const size_t go = (size_t)(block_q0 + qi) * C;
        for (int ch = l; ch < C; ch += 64) {
            out[go + ch] = wa * feats[ga + ch] + wb * feats[gb + ch] + wc * feats[gc + ch];
        }
    }
}

#define FQPB 256
extern "C" __global__ void __launch_bounds__(FQPB)
knn3_fallback(const float* __restrict__ xyz,
              const float* __restrict__ new_xyz,
              const float* __restrict__ feats,
              float* __restrict__ out,
              int mb, int nb, int C)
{
    extern __shared__ float4 s_pts[];
    const int tid      = threadIdx.x;
    const int block_q0 = blockIdx.x * FQPB;
    const int batch    = block_q0 / nb;
    const int known0   = batch * mb;
    for (int p = tid; p < mb; p += FQPB) {
        const float px = xyz[(size_t)(known0 + p) * 3 + 0];
        const float py = xyz[(size_t)(known0 + p) * 3 + 1];
        const float pz = xyz[(size_t)(known0 + p) * 3 + 2];
        float pn;
        {
#pragma clang fp contract(off)
            pn = (px * px + py * py) + pz * pz;
        }
        s_pts[p] = make_float4(px, py, pz, pn);
    }
    __syncthreads();
    const int gq = block_q0 + tid;
    const float qx = new_xyz[(size_t)gq * 3 + 0];
    const float qy = new_xyz[(size_t)gq * 3 + 1];
    const float qz = new_xyz[(size_t)gq * 3 + 2];
    float qq;
    {
#pragma clang fp contract(off)
        qq = (qx * qx + qy * qy) + qz * qz;
    }
    float b0 = INFINITY, b1 = INFINITY, b2 = INFINITY;
    int   i0 = 0, i1 = 0, i2 = 0;
#pragma unroll 8
    for (int p = 0; p < mb; ++p) {
        const float4 P = s_pts[p];
        const float dot = fmaf(qz, P.z, fmaf(qy, P.y, qx * P.x));
        const float d2  = fmaf(-2.0f, dot, qq) + P.w;
        const bool c0 = d2 < b0;
        const bool c1 = d2 < b1;
        const bool c2 = d2 < b2;
        b2 = c1 ? b1 : (c2 ? d2 : b2);
        i2 = c1 ? i1 : (c2 ? p  : i2);
        b1 = c0 ? b0 : (c1 ? d2 : b1);
        i1 = c0 ? i0 : (c1 ? p  : i1);
        b0 = c0 ? d2 : b0;
        i0 = c0 ? p  : i0;
    }
    const float da = sqrtf(fmaxf(b0, 0.0f));
    const float db = sqrtf(fmaxf(b1, 0.0f));
    const float dc = sqrtf(fmaxf(b2, 0.0f));
    const float ra = 1.0f / (da + 1e-8f);
    const float rb = 1.0f / (db + 1e-8f);
    const float rc = 1.0f / (dc + 1e-8f);
    float rs;
    {
#pragma clang fp contract(off)
        rs = (ra + rb) + rc;
    }
    const float wa = ra / rs, wb = rb / rs, wc = rc / rs;
    const size_t ga = (size_t)(known0 + i0) * C;
    const size_t gb = (size_t)(known0 + i1) * C;
    const size_t gc = (size_t)(known0 + i2) * C;
    const size_t go = (size_t)gq * C;
    for (int ch = 0; ch < C; ++ch) {
        out[go + ch] = wa * feats[ga + ch] + wb * feats[gb + ch] + wc * feats[gc + ch];
    }
}

extern "C" void kernel_launch(void* const* d_in, const int* in_sizes, int n_in,
                              void* d_out, int out_size, void* d_ws, size_t ws_size,
                              hipStream_t stream) {
    const float* xyz     = (const float*)d_in[0];
    const float* new_xyz = (const float*)d_in[2];
    const float* feats   = (const float*)d_in[4];
    float*       out     = (float*)d_out;

    const int n_known = in_sizes[0] / 3;
    const int B       = in_sizes[1];
    const int n_query = in_sizes[2] / 3;
    const int C       = in_sizes[4] / n_known;
    const int mb      = n_known / B;
    const int nb      = n_query / B;

    // workspace layout for the windowed path
    char* wp = (char*)d_ws;
    float4* ps   = (float4*)wp;  wp += (size_t)B * mb * sizeof(float4);
    int*    pidx = (int*)wp;     wp += (size_t)B * mb * sizeof(int);
    int*    qord = (int*)wp;     wp += (size_t)B * nb * sizeof(int);
    int*    boff = (int*)wp;     wp += (size_t)B * (NBIN + 1) * sizeof(int);
    const size_t need = (size_t)(wp - (char*)d_ws);

    if (ws_size >= need && (nb % WQPB) == 0 && mb >= 3) {
        build1d<<<2 * B, BTH1, 0, stream>>>(xyz, new_xyz, mb, nb, ps, pidx, qord, boff);
        knn_win<<<(B * nb) / WQPB, WTH, 0, stream>>>(
            new_xyz, feats, qord, boff, ps, pidx, out, mb, nb, C);
    } else if ((nb % QPB) == 0) {
        const size_t smem_chunk = (size_t)CHUNK * sizeof(float4);
        const size_t smem_merge = (size_t)(6 * WAVES * QPB + 6 * QPB) * sizeof(float);
        const size_t shmem = smem_chunk > smem_merge ? smem_chunk : smem_merge;
        knn3_v5<<<n_query / QPB, THREADS, shmem, stream>>>(
            xyz, new_xyz, feats, out, mb, nb, C);
    } else {
        const size_t shmem = (size_t)mb * sizeof(float4);
        knn3_fallback<<<(n_query + FQPB - 1) / FQPB, FQPB, shmem, stream>>>(
            xyz, new_xyz, feats, out, mb, nb, C);
    }
}